// Round 10
// baseline (192.923 us; speedup 1.0000x reference)
//
#include <hip/hip_runtime.h>
#include <hip/hip_bf16.h>
#include <stdint.h>

// ---------- types ----------
typedef _Float16 half2v __attribute__((ext_vector_type(2)));
typedef _Float16 half8v __attribute__((ext_vector_type(8)));
typedef uint32_t u32x4  __attribute__((ext_vector_type(4)));
typedef float    f32x4  __attribute__((ext_vector_type(4)));

__device__ __forceinline__ unsigned short f2h(float f) {
  _Float16 h = (_Float16)f;
  return __builtin_bit_cast(unsigned short, h);
}
__device__ __forceinline__ half2v bch2(uint32_t u) {
  return __builtin_bit_cast(half2v, u);
}
__device__ __forceinline__ uint32_t pkrtz_u32(float a, float b) {
  return __builtin_bit_cast(uint32_t, __builtin_amdgcn_cvt_pkrtz(a, b));
}

// Window-major qkv layout. Element index (channel 0 of head n) for pixel (h,w),
// within one tensor's 32MB region (16M f16 elems; includes the half offset).
//  half 0 (horizontal stripes): [b][n][s=h>>3][w][qr=h&7][cc]
//  half 1 (vertical stripes):   [b][n][h][s=w>>3][qr=w&7][cc]  (s*256+qr*32 == w*32)
__device__ __forceinline__ int qkv_idx(int half, int b, int n, int h, int w) {
  int idx = half * 8388608 + (b * 8 + n) * 131072;
  idx += (half == 0) ? ((h >> 3) * 16384 + w * 256 + (h & 7) * 32)
                     : (h * 2048 + w * 32);
  return idx;
}

// async global->LDS, 16 bytes per lane. lbase must be wave-uniform.
#define GLOAD_LDS16(gsrc, lbase)                                          \
  __builtin_amdgcn_global_load_lds(                                       \
      (const __attribute__((address_space(1))) uint32_t*)(gsrc),          \
      (__attribute__((address_space(3))) uint32_t*)(lbase), 16, 0, 0)

// ---------- f32 -> f16 conversion (4 elems/thread) ----------
__global__ __launch_bounds__(256) void cvt_f32_f16(const float* __restrict__ in,
                                                   unsigned short* __restrict__ out,
                                                   int n4) {
  int i = blockIdx.x * 256 + threadIdx.x;
  if (i >= n4) return;
  float4 f = reinterpret_cast<const float4*>(in)[i];
  ushort4 u;
  u.x = f2h(f.x); u.y = f2h(f.y); u.z = f2h(f.z); u.w = f2h(f.w);
  reinterpret_cast<ushort4*>(out)[i] = u;
}

// ---------- f16 GEMM, C[m,n] = sum_k A[m,k]*B[n,k]  (A: MxK, B: NxK row-major)
// 256x256 tile, 8 waves (2M x 4N), wave tile 128x64 = 8x4 frags, MFMA 16x16x32.
// FOUR LDS buffers of one BK=32 (A,B) sub-tile each (4 x 32KB = 128KB):
// 3-deep prefetch, counted vmcnt(12/8/4/0) + raw s_barrier pair per K-step —
// same proven sync skeleton as the 2-buffer version, just deeper & bigger.
// Race argument: tile-t visibility = own vmcnt + barrier1; buffer overwrite
// (t+3 = t-1 mod 4) protected by barrier2 after t-1's compute.
// 1D grid + bijective XCD swizzle (nwg%8==0), n-fast within each XCD chunk.
// Operand-swapped MFMA epilogue (lane holds 4 contiguous n at one m).
// LDS k-slot XOR swizzle (pre-swizzled global source; linear gload_lds dest).
// MODE 0: f32 out + bias, token-major (GEMM2).
// MODE 1: f16 out scattered to window-major qkv regions (GEMM1, N=1536).
template<int MODE>
__global__ __launch_bounds__(512, 2) void gemm_bt(
    const unsigned short* __restrict__ A,
    const unsigned short* __restrict__ B,
    unsigned short* __restrict__ Cq,
    float* __restrict__ Cf,
    const float* __restrict__ bias,
    int M, int N, int K)
{
  __shared__ unsigned short As[4][256 * 32];   // 4 x 16KB
  __shared__ unsigned short Bs[4][256 * 32];   // 4 x 16KB
  const int tid  = threadIdx.x;
  // --- XCD-swizzled tile assignment (nwg % 8 == 0 -> bijective) ---
  const int gn   = N >> 8;
  const int cpx  = gridDim.x >> 3;
  const int bid  = blockIdx.x;
  const int wgid = (bid & 7) * cpx + (bid >> 3);
  const int m0   = (wgid / gn) * 256;
  const int n0   = (wgid % gn) * 256;
  const int wave = tid >> 6, lane = tid & 63;
  const int wr  = wave >> 2;          // 0..1  (m-half, 128 rows)
  const int wcn = wave & 3;           // 0..3  (n-quarter, 64 cols)
  const int sr = tid >> 2;                                // staging row 0..127
  const int sc = ((tid & 3) ^ ((tid >> 3) & 3)) * 8;      // pre-swizzled k-chunk
  const size_t aBase0 = (size_t)(m0 + sr) * K + sc;
  const size_t aBase1 = (size_t)(m0 + 128 + sr) * K + sc;
  const size_t bBase0 = (size_t)(n0 + sr) * K + sc;
  const size_t bBase1 = (size_t)(n0 + 128 + sr) * K + sc;
  // per-thread LDS dest is linear tid*16B within each 8KB issue; wave-uniform base
  char* ldsA = (char*)(&As[0][0]) + (tid & ~63) * 16;
  char* ldsB = (char*)(&Bs[0][0]) + (tid & ~63) * 16;

#define STAGE_TILE(bsel, kofs)                                      \
  do {                                                              \
    GLOAD_LDS16(A + aBase0 + (kofs), ldsA + (bsel) * 16384);        \
    GLOAD_LDS16(A + aBase1 + (kofs), ldsA + (bsel) * 16384 + 8192); \
    GLOAD_LDS16(B + bBase0 + (kofs), ldsB + (bsel) * 16384);        \
    GLOAD_LDS16(B + bBase1 + (kofs), ldsB + (bsel) * 16384 + 8192); \
  } while (0)

  // prologue: stage tiles 0,1,2 (12 loads in flight)
  STAGE_TILE(0, 0);
  STAGE_TILE(1, 32);
  STAGE_TILE(2, 64);

  f32x4 acc[8][4];
  const f32x4 zero = {0.f, 0.f, 0.f, 0.f};
  #pragma unroll
  for (int i = 0; i < 8; ++i)
    #pragma unroll
    for (int j = 0; j < 4; ++j) acc[i][j] = zero;

  const int lr   = lane & 15;
  const int slot = (lane >> 4) ^ ((lr >> 1) & 3);   // swizzled k-slot (elems/8)

  auto compute = [&](const unsigned short* Asb, const unsigned short* Bsb) {
    half8v bf[4];
    #pragma unroll
    for (int j = 0; j < 4; ++j)
      bf[j] = *reinterpret_cast<const half8v*>(Bsb + (wcn * 64 + j * 16 + lr) * 32 + slot * 8);
    half8v af[8];
    #pragma unroll
    for (int i = 0; i < 8; ++i)
      af[i] = *reinterpret_cast<const half8v*>(Asb + (wr * 128 + i * 16 + lr) * 32 + slot * 8);
    __builtin_amdgcn_s_setprio(1);
    #pragma unroll
    for (int i = 0; i < 8; ++i)
      #pragma unroll
      for (int j = 0; j < 4; ++j)
        acc[i][j] = __builtin_amdgcn_mfma_f32_16x16x32_f16(bf[j], af[i], acc[i][j], 0, 0, 0);
    __builtin_amdgcn_s_setprio(0);
  };

  const int nt = K >> 5;   // K/32 sub-tiles (=16 for K=512)
  for (int t = 0; t < nt; ++t) {
    if (t + 3 < nt) STAGE_TILE((t + 3) & 3, (t + 3) * 32);  // 3-deep prefetch
    // counted wait: allow tiles t+1..t+3 (4 loads each) to stay in flight
    if (t < nt - 3)       asm volatile("s_waitcnt vmcnt(12)" ::: "memory");
    else if (t == nt - 3) asm volatile("s_waitcnt vmcnt(8)"  ::: "memory");
    else if (t == nt - 2) asm volatile("s_waitcnt vmcnt(4)"  ::: "memory");
    else                  asm volatile("s_waitcnt vmcnt(0)"  ::: "memory");
    __builtin_amdgcn_s_barrier();                    // tile t visible to all
    __builtin_amdgcn_sched_barrier(0);
    compute(&As[t & 3][0], &Bs[t & 3][0]);
    __builtin_amdgcn_s_barrier();                    // all done reading buf[t&3]
    __builtin_amdgcn_sched_barrier(0);
  }
#undef STAGE_TILE

  // D layout (operand-swapped): row (n-dim) = (lane>>4)*4 + e, col (m-dim) = lane&15
  const int cr = (lane >> 4) * 4;   // channel offset (4 contiguous)
  const int cc = lane & 15;         // token offset

  if constexpr (MODE == 0) {
    #pragma unroll
    for (int j = 0; j < 4; ++j) {
      const int n = n0 + wcn * 64 + j * 16 + cr;
      const float4 b4 = *reinterpret_cast<const float4*>(bias + n);
      #pragma unroll
      for (int i = 0; i < 8; ++i) {
        const int m = m0 + wr * 128 + i * 16 + cc;
        float4 r;
        r.x = acc[i][j][0] + b4.x;
        r.y = acc[i][j][1] + b4.y;
        r.z = acc[i][j][2] + b4.z;
        r.w = acc[i][j][3] + b4.w;
        *reinterpret_cast<float4*>(Cf + (size_t)m * N + n) = r;
      }
    }
  } else {
    const int mb   = m0 + wr * 128;   // token base (wave-uniform, 128-aligned)
    const int btok = mb >> 12;
    const int hr0  = (mb >> 6) & 63;  // even; wave spans h-rows hr0, hr0+1
    #pragma unroll
    for (int j = 0; j < 4; ++j) {
      const int nb    = n0 + wcn * 64 + j * 16 + cr;  // 4 contiguous channels
      const int tq    = nb >> 9;                      // 0=q 1=k 2=v
      const int halfc = (nb >> 8) & 1;
      const int nn    = (nb & 255) >> 5;
      const int ch4   = nb & 31;
      const int headbase = tq * 16777216 + halfc * 8388608 +
                           (btok * 8 + nn) * 131072 + ch4;
      #pragma unroll
      for (int i = 0; i < 8; ++i) {
        const int hrow = hr0 + (i >> 2);
        const int wpix = (i & 3) * 16 + cc;
        const int off = halfc ? (hrow * 2048 + wpix * 32)
                              : ((hrow >> 3) * 16384 + wpix * 256 + (hrow & 7) * 32);
        uint2 r;
        r.x = pkrtz_u32(acc[i][j][0], acc[i][j][1]);
        r.y = pkrtz_u32(acc[i][j][2], acc[i][j][3]);
        *reinterpret_cast<uint2*>(Cq + headbase + off) = r;
      }
    }
  }
}

// ---------- stripe attention + LePE, TWO windows per wave ----------
// qkvp: q (32MB) | k (32MB) | v (32MB), f16, window-major.
// wlep: f16 LePE weights [half][tap(9)][256].
// outp: token-major 32768 x 512 f16.
__global__ __launch_bounds__(256) void attn_lepe(
    const unsigned short* __restrict__ qkvp,
    const unsigned short* __restrict__ wlep,
    unsigned short* __restrict__ outp)
{
  const int gw   = (int)((blockIdx.x * 256 + threadIdx.x) >> 6);  // pair index
  const int lane = threadIdx.x & 63;
  const int half = gw >> 14;
  const int id   = gw & 16383;
  const int b    = id >> 11;
  const int n    = (id >> 8) & 7;
  int h0, w0;
  if (half == 0) { h0 = ((id >> 5) & 7) * 8; w0 = (id & 31) * 2; }
  else           { h0 = ((id >> 3) & 31) * 2; w0 = (id & 7) * 8; }
  const int baseA = qkv_idx(half, b, n, h0, w0);
  const int dWin  = (half == 0) ? 256 : 2048;   // adjacent-window offset
  const int baseB = baseA + dWin;

  // ---- QK^T for both windows: lane = (qr, kr) ----
  const int qr = lane >> 3, kr = lane & 7;
  const unsigned short* qA = qkvp + baseA + qr * 32;
  const unsigned short* kA = qkvp + 16777216 + baseA + kr * 32;
  float sA = 0.f, sB = 0.f;
  #pragma unroll
  for (int c = 0; c < 4; ++c) {
    const u32x4 qa = *reinterpret_cast<const u32x4*>(qA + c * 8);
    const u32x4 ka = *reinterpret_cast<const u32x4*>(kA + c * 8);
    const u32x4 qb = *reinterpret_cast<const u32x4*>(qA + dWin + c * 8);
    const u32x4 kb = *reinterpret_cast<const u32x4*>(kA + dWin + c * 8);
    #pragma unroll
    for (int e = 0; e < 4; ++e) {
      sA = __builtin_amdgcn_fdot2(bch2(qa[e]), bch2(ka[e]), sA, false);
      sB = __builtin_amdgcn_fdot2(bch2(qb[e]), bch2(kb[e]), sB, false);
    }
  }
  const float scl = 0.17677669529663687f;  // 1/sqrt(32)
  const float pA = __expf(sA * scl);
  const float pB = __expf(sB * scl);
  float denA = pA, denB = pB;
  denA += __shfl_xor(denA, 1); denA += __shfl_xor(denA, 2); denA += __shfl_xor(denA, 4);
  denB += __shfl_xor(denB, 1); denB += __shfl_xor(denB, 2); denB += __shfl_xor(denB, 4);
  const float aAv = pA * __builtin_amdgcn_rcpf(denA);
  const float aBv = pB * __builtin_amdgcn_rcpf(denB);
  const uint32_t adu = pkrtz_u32(aAv, aBv);   // lo = winA, hi = winB

  // ---- PV: lane = (qr2, win, dgrp); 16B vectors over 8 channels ----
  const int dgrp = lane & 3;
  const int win  = (lane >> 2) & 1;
  const int qr2  = lane >> 3;
  const int d0   = dgrp * 8;
  const int mybase = win ? baseB : baseA;
  const unsigned short* vwin = qkvp + 33554432 + mybase;

  half2v o01 = {0,0}, o23 = {0,0}, o45 = {0,0}, o67 = {0,0};
  #pragma unroll
  for (int k = 0; k < 8; ++k) {
    const uint32_t pairw = (uint32_t)__shfl((int)adu, qr2 * 8 + k);
    const half2v ph = bch2(pairw);
    const _Float16 av = win ? ph.y : ph.x;
    const half2v ak2 = {av, av};
    const u32x4 vv = *reinterpret_cast<const u32x4*>(vwin + k * 32 + d0);
    o01 += ak2 * bch2(vv[0]);
    o23 += ak2 * bch2(vv[1]);
    o45 += ak2 * bch2(vv[2]);
    o67 += ak2 * bch2(vv[3]);
  }

  // ---- LePE: depthwise 3x3 on v (zero-pad SAME) at this lane's pixel ----
  const int hq = (half == 0) ? (h0 + qr2) : (h0 + win);
  const int wq = (half == 0) ? (w0 + win) : (w0 + qr2);
  const unsigned short* vplane = qkvp + 33554432;
  const unsigned short* wl = wlep + half * 2304 + n * 32 + d0;
  half2v l01 = {0,0}, l23 = {0,0}, l45 = {0,0}, l67 = {0,0};
  #pragma unroll
  for (int dy = -1; dy <= 1; ++dy) {
    #pragma unroll
    for (int dx = -1; dx <= 1; ++dx) {
      const int hh = hq + dy, ww = wq + dx;
      u32x4 vv = {0u, 0u, 0u, 0u};
      if ((unsigned)hh < 64u && (unsigned)ww < 64u)
        vv = *reinterpret_cast<const u32x4*>(vplane + qkv_idx(half, b, n, hh, ww) + d0);
      const u32x4 wt = *reinterpret_cast<const u32x4*>(wl + ((dy + 1) * 3 + dx + 1) * 256);
      l01 += bch2(wt[0]) * bch2(vv[0]);
      l23 += bch2(wt[1]) * bch2(vv[1]);
      l45 += bch2(wt[2]) * bch2(vv[2]);
      l67 += bch2(wt[3]) * bch2(vv[3]);
    }
  }

  // ---- store token-major for GEMM2 (16B per lane) ----
  const int m = b * 4096 + hq * 64 + wq;
  const int chan0 = half * 256 + n * 32;
  u32x4 r;
  r[0] = __builtin_bit_cast(uint32_t, (half2v)(o01 + l01));
  r[1] = __builtin_bit_cast(uint32_t, (half2v)(o23 + l23));
  r[2] = __builtin_bit_cast(uint32_t, (half2v)(o45 + l45));
  r[3] = __builtin_bit_cast(uint32_t, (half2v)(o67 + l67));
  *reinterpret_cast<u32x4*>(outp + (size_t)m * 512 + chan0 + d0) = r;
}

// ---------- launch ----------
extern "C" void kernel_launch(void* const* d_in, const int* in_sizes, int n_in,
                              void* d_out, int out_size, void* d_ws, size_t ws_size,
                              hipStream_t stream) {
  const float* x      = (const float*)d_in[0];   // (8, 4096, 512)
  const float* w_qkv  = (const float*)d_in[1];   // (1536, 512)
  const float* w_proj = (const float*)d_in[2];   // (512, 512)
  const float* b_proj = (const float*)d_in[3];   // (512,)
  const float* lepe_h = (const float*)d_in[4];   // (3,3,1,256)
  const float* lepe_v = (const float*)d_in[5];   // (3,3,1,256)
  float* out = (float*)d_out;                    // (8, 4096, 512) f32

  char* ws = (char*)d_ws;
  unsigned short* qkv_p   = (unsigned short*)ws;                 // 96MB: q|k|v window-major
  unsigned short* xh      = (unsigned short*)(ws + 100663296);   // 32MB: x f16; reused as attn_out
  unsigned short* wqkv_h  = (unsigned short*)(ws + 134217728);   // 1536*512 f16
  unsigned short* wproj_h = (unsigned short*)(ws + 135790592);   // 512*512 f16
  unsigned short* wlep_h  = (unsigned short*)(ws + 136314880);   // 2*9*256 f16

  // casts
  cvt_f32_f16<<<16384, 256, 0, stream>>>(x, xh, 4194304);
  cvt_f32_f16<<<768,   256, 0, stream>>>(w_qkv, wqkv_h, 196608);
  cvt_f32_f16<<<256,   256, 0, stream>>>(w_proj, wproj_h, 65536);
  cvt_f32_f16<<<3,     256, 0, stream>>>(lepe_h, wlep_h, 576);
  cvt_f32_f16<<<3,     256, 0, stream>>>(lepe_v, wlep_h + 2304, 576);

  // qkv = x @ w_qkv^T -> window-major f16 regions (256^2 tiles, XCD-swizzled)
  gemm_bt<1><<<768, 512, 0, stream>>>(
      xh, wqkv_h, qkv_p, nullptr, nullptr, 32768, 1536, 512);

  // stripe attention + LePE -> attn_out token-major (xh region; xh dead)
  attn_lepe<<<8192, 256, 0, stream>>>(qkv_p, wlep_h, xh);

  // out = attn_out @ w_proj^T + b_proj -> f32
  gemm_bt<0><<<256, 512, 0, stream>>>(
      xh, wproj_h, nullptr, out, b_proj, 32768, 512, 512);
}

// Round 11
// 186.961 us; speedup vs baseline: 1.0319x; 1.0319x over previous
//
#include <hip/hip_runtime.h>
#include <hip/hip_bf16.h>
#include <stdint.h>

// ---------- types ----------
typedef _Float16 half2v __attribute__((ext_vector_type(2)));
typedef _Float16 half8v __attribute__((ext_vector_type(8)));
typedef uint32_t u32x4  __attribute__((ext_vector_type(4)));
typedef float    f32x4  __attribute__((ext_vector_type(4)));

__device__ __forceinline__ unsigned short f2h(float f) {
  _Float16 h = (_Float16)f;
  return __builtin_bit_cast(unsigned short, h);
}
__device__ __forceinline__ half2v bch2(uint32_t u) {
  return __builtin_bit_cast(half2v, u);
}
__device__ __forceinline__ uint32_t pkrtz_u32(float a, float b) {
  return __builtin_bit_cast(uint32_t, __builtin_amdgcn_cvt_pkrtz(a, b));
}

// Window-major qkv layout. Element index (channel 0 of head n) for pixel (h,w),
// within one tensor's 32MB region (16M f16 elems; includes the half offset).
//  half 0 (horizontal stripes): [b][n][s=h>>3][w][qr=h&7][cc]
//  half 1 (vertical stripes):   [b][n][h][s=w>>3][qr=w&7][cc]
__device__ __forceinline__ int qkv_idx(int half, int b, int n, int h, int w) {
  int idx = half * 8388608 + (b * 8 + n) * 131072;
  idx += (half == 0) ? ((h >> 3) * 16384 + w * 256 + (h & 7) * 32)
                     : (h * 2048 + w * 32);
  return idx;
}

// async global->LDS, 16 bytes per lane. lbase must be wave-uniform.
#define GLOAD_LDS16(gsrc, lbase)                                          \
  __builtin_amdgcn_global_load_lds(                                       \
      (const __attribute__((address_space(1))) uint32_t*)(gsrc),          \
      (__attribute__((address_space(3))) uint32_t*)(lbase), 16, 0, 0)

// ---------- f32 -> f16 conversion (weights only; 4 elems/thread) ----------
__global__ __launch_bounds__(256) void cvt_f32_f16(const float* __restrict__ in,
                                                   unsigned short* __restrict__ out,
                                                   int n4) {
  int i = blockIdx.x * 256 + threadIdx.x;
  if (i >= n4) return;
  float4 f = reinterpret_cast<const float4*>(in)[i];
  ushort4 u;
  u.x = f2h(f.x); u.y = f2h(f.y); u.z = f2h(f.z); u.w = f2h(f.w);
  reinterpret_cast<ushort4*>(out)[i] = u;
}

// ---------- GEMM1: qkv = x(f32) @ w_qkv(f16)^T -> window-major f16 ----------
// A staged DIRECTLY from f32 x via global_load_lds (fuses away the x-cast):
// 4 A-issues (32 rows x 128B each) + 2 B-issues per BK=32 step; f32->f16 via
// v_cvt_pkrtz at fragment read. 128x128 tile, 4 waves, MFMA 16x16x32 f16.
// R9-proven T4 skeleton: dbuf LDS, stage t+1 before compute t, counted
// vmcnt(6) (never 0 in loop) + raw s_barrier pair. 1D grid, bijective XCD
// swizzle, n-fast within XCD chunk. Operand-swapped packed epilogue.
// A swizzle: LDS[row][pos16B] holds global 16B-chunk pos^(row&7) (involution).
__global__ __launch_bounds__(256) void gemm_qkv(
    const float* __restrict__ X,           // 32768 x 512 f32
    const unsigned short* __restrict__ B,  // 1536 x 512 f16
    unsigned short* __restrict__ Cq)
{
  constexpr int K = 512, N = 1536;
  __shared__ float          Af[2][128 * 32];   // 2 x 16KB
  __shared__ unsigned short Bh[2][128 * 32];   // 2 x 8KB
  const int tid  = threadIdx.x;
  const int gn   = N >> 7;                 // 12
  const int cpx  = gridDim.x >> 3;
  const int bid  = blockIdx.x;
  const int wgid = (bid & 7) * cpx + (bid >> 3);
  const int m0   = (wgid / gn) * 128;
  const int n0   = (wgid % gn) * 128;
  const int wave = tid >> 6, lane = tid & 63;
  const int wr = wave >> 1, wc = wave & 1;
  // B staging (f16, R9 pattern): row sr, pre-swizzled 16B slot
  const int sr  = tid >> 2;
  const int scB = ((tid & 3) ^ ((tid >> 3) & 3)) * 8;
  const size_t bBase0 = (size_t)(n0 + sr) * K + scB;
  const size_t bBase1 = (size_t)(n0 + 64 + sr) * K + scB;
  // A staging (f32): per issue 32 rows x 8 chunks(16B); row=tid>>3, c=tid&7
  const int arow = tid >> 3;                       // 0..31
  const int acsw = ((tid & 7) ^ (arow & 7)) * 4;   // pre-swizzled f32 col
  const size_t aBase = (size_t)(m0 + arow) * K + acsw;
  char* ldsA = (char*)(&Af[0][0]) + (tid & ~63) * 16;
  char* ldsB = (char*)(&Bh[0][0]) + (tid & ~63) * 16;

#define STAGE_Q(bsel, kt)                                                \
  do {                                                                   \
    GLOAD_LDS16(X + aBase + (kt),            ldsA + (bsel) * 16384);     \
    GLOAD_LDS16(X + aBase + 32 * K + (kt),   ldsA + (bsel) * 16384 + 4096); \
    GLOAD_LDS16(X + aBase + 64 * K + (kt),   ldsA + (bsel) * 16384 + 8192); \
    GLOAD_LDS16(X + aBase + 96 * K + (kt),   ldsA + (bsel) * 16384 + 12288);\
    GLOAD_LDS16(B + bBase0 + (kt),           ldsB + (bsel) * 8192);      \
    GLOAD_LDS16(B + bBase1 + (kt),           ldsB + (bsel) * 8192 + 4096);  \
  } while (0)

  STAGE_Q(0, 0);

  f32x4 acc[4][4];
  const f32x4 zero = {0.f, 0.f, 0.f, 0.f};
  #pragma unroll
  for (int i = 0; i < 4; ++i)
    #pragma unroll
    for (int j = 0; j < 4; ++j) acc[i][j] = zero;

  const int lr    = lane & 15;
  const int kg    = lane >> 4;                 // k-group 0..3 (8 K-elems)
  const int slotB = kg ^ ((lr >> 1) & 3);      // B swizzled slot (8 f16)
  const int pA0   = (2 * kg)     ^ (lr & 7);   // A swizzled 16B chunks
  const int pA1   = (2 * kg + 1) ^ (lr & 7);

  auto compute = [&](const float* Asb, const unsigned short* Bsb) {
    half8v bfr[4], af[4];
    #pragma unroll
    for (int j = 0; j < 4; ++j)
      bfr[j] = *reinterpret_cast<const half8v*>(Bsb + (wc * 64 + j * 16 + lr) * 32 + slotB * 8);
    #pragma unroll
    for (int i = 0; i < 4; ++i) {
      const float* rowp = Asb + (wr * 64 + i * 16 + lr) * 32;
      const float4 fa = *reinterpret_cast<const float4*>(rowp + pA0 * 4);
      const float4 fb = *reinterpret_cast<const float4*>(rowp + pA1 * 4);
      u32x4 pk;
      pk[0] = pkrtz_u32(fa.x, fa.y);
      pk[1] = pkrtz_u32(fa.z, fa.w);
      pk[2] = pkrtz_u32(fb.x, fb.y);
      pk[3] = pkrtz_u32(fb.z, fb.w);
      af[i] = __builtin_bit_cast(half8v, pk);
    }
    __builtin_amdgcn_s_setprio(1);
    #pragma unroll
    for (int i = 0; i < 4; ++i)
      #pragma unroll
      for (int j = 0; j < 4; ++j)
        acc[i][j] = __builtin_amdgcn_mfma_f32_16x16x32_f16(bfr[j], af[i], acc[i][j], 0, 0, 0);
    __builtin_amdgcn_s_setprio(0);
  };

  const int nt = K >> 5;   // 16
  for (int t = 0; t < nt - 1; ++t) {
    STAGE_Q((t + 1) & 1, (t + 1) * 32);              // issue next-tile loads
    asm volatile("s_waitcnt vmcnt(6)" ::: "memory"); // tile t done; t+1 in flight
    __builtin_amdgcn_s_barrier();
    __builtin_amdgcn_sched_barrier(0);
    compute(&Af[t & 1][0], &Bh[t & 1][0]);
    __builtin_amdgcn_s_barrier();
    __builtin_amdgcn_sched_barrier(0);
  }
  asm volatile("s_waitcnt vmcnt(0)" ::: "memory");
  __builtin_amdgcn_s_barrier();
  __builtin_amdgcn_sched_barrier(0);
  compute(&Af[(nt - 1) & 1][0], &Bh[(nt - 1) & 1][0]);
#undef STAGE_Q

  // D layout (operand-swapped): row(n) = (lane>>4)*4 + e, col(m) = lane&15
  const int cr = (lane >> 4) * 4;
  const int cc = lane & 15;
  const int mb   = m0 + wr * 64;
  const int btok = mb >> 12;
  const int htok = (mb >> 6) & 63;
  #pragma unroll
  for (int j = 0; j < 4; ++j) {
    const int nb    = n0 + wc * 64 + j * 16 + cr;  // 4 contiguous channels
    const int tq    = nb >> 9;
    const int halfc = (nb >> 8) & 1;
    const int nn    = (nb & 255) >> 5;
    const int ch4   = nb & 31;
    int base = tq * 16777216 + halfc * 8388608 + (btok * 8 + nn) * 131072 + ch4;
    base += halfc ? (htok * 2048) : ((htok >> 3) * 16384 + (htok & 7) * 32);
    const int wstride = halfc ? 32 : 256;
    #pragma unroll
    for (int i = 0; i < 4; ++i) {
      const int wpix = i * 16 + cc;
      uint2 r;
      r.x = pkrtz_u32(acc[i][j][0], acc[i][j][1]);
      r.y = pkrtz_u32(acc[i][j][2], acc[i][j][3]);
      *reinterpret_cast<uint2*>(Cq + base + wpix * wstride) = r;
    }
  }
}

// ---------- GEMM2: out = attn_out(f16) @ w_proj(f16)^T + bias -> f32 ----------
// Verbatim R9 MODE-0 path (proven 128x128, gload_lds, counted vmcnt(4)).
__global__ __launch_bounds__(256) void gemm_proj(
    const unsigned short* __restrict__ A,
    const unsigned short* __restrict__ B,
    float* __restrict__ Cf,
    const float* __restrict__ bias)
{
  constexpr int K = 512, N = 512;
  __shared__ unsigned short As[2][128 * 32];
  __shared__ unsigned short Bs[2][128 * 32];
  const int tid  = threadIdx.x;
  const int gn   = N >> 7;                 // 4
  const int cpx  = gridDim.x >> 3;
  const int bid  = blockIdx.x;
  const int wgid = (bid & 7) * cpx + (bid >> 3);
  const int m0   = (wgid / gn) * 128;
  const int n0   = (wgid % gn) * 128;
  const int wave = tid >> 6, lane = tid & 63;
  const int wr = wave >> 1, wc = wave & 1;
  const int sr = tid >> 2;
  const int sc = ((tid & 3) ^ ((tid >> 3) & 3)) * 8;
  const size_t aBase0 = (size_t)(m0 + sr) * K + sc;
  const size_t aBase1 = (size_t)(m0 + 64 + sr) * K + sc;
  const size_t bBase0 = (size_t)(n0 + sr) * K + sc;
  const size_t bBase1 = (size_t)(n0 + 64 + sr) * K + sc;
  char* ldsA = (char*)(&As[0][0]) + (tid & ~63) * 16;
  char* ldsB = (char*)(&Bs[0][0]) + (tid & ~63) * 16;

#define STAGE_P(bsel, kofs)                                        \
  do {                                                             \
    GLOAD_LDS16(A + aBase0 + (kofs), ldsA + (bsel) * 8192);        \
    GLOAD_LDS16(A + aBase1 + (kofs), ldsA + (bsel) * 8192 + 4096); \
    GLOAD_LDS16(B + bBase0 + (kofs), ldsB + (bsel) * 8192);        \
    GLOAD_LDS16(B + bBase1 + (kofs), ldsB + (bsel) * 8192 + 4096); \
  } while (0)

  STAGE_P(0, 0);

  f32x4 acc[4][4];
  const f32x4 zero = {0.f, 0.f, 0.f, 0.f};
  #pragma unroll
  for (int i = 0; i < 4; ++i)
    #pragma unroll
    for (int j = 0; j < 4; ++j) acc[i][j] = zero;

  const int lr   = lane & 15;
  const int slot = (lane >> 4) ^ ((lr >> 1) & 3);

  auto compute = [&](const unsigned short* Asb, const unsigned short* Bsb) {
    half8v af[4], bfr[4];
    #pragma unroll
    for (int i = 0; i < 4; ++i)
      af[i] = *reinterpret_cast<const half8v*>(Asb + (wr * 64 + i * 16 + lr) * 32 + slot * 8);
    #pragma unroll
    for (int j = 0; j < 4; ++j)
      bfr[j] = *reinterpret_cast<const half8v*>(Bsb + (wc * 64 + j * 16 + lr) * 32 + slot * 8);
    __builtin_amdgcn_s_setprio(1);
    #pragma unroll
    for (int i = 0; i < 4; ++i)
      #pragma unroll
      for (int j = 0; j < 4; ++j)
        acc[i][j] = __builtin_amdgcn_mfma_f32_16x16x32_f16(bfr[j], af[i], acc[i][j], 0, 0, 0);
    __builtin_amdgcn_s_setprio(0);
  };

  const int nt = K >> 5;
  for (int t = 0; t < nt - 1; ++t) {
    STAGE_P((t + 1) & 1, (t + 1) * 32);
    asm volatile("s_waitcnt vmcnt(4)" ::: "memory");
    __builtin_amdgcn_s_barrier();
    __builtin_amdgcn_sched_barrier(0);
    compute(&As[t & 1][0], &Bs[t & 1][0]);
    __builtin_amdgcn_s_barrier();
    __builtin_amdgcn_sched_barrier(0);
  }
  asm volatile("s_waitcnt vmcnt(0)" ::: "memory");
  __builtin_amdgcn_s_barrier();
  __builtin_amdgcn_sched_barrier(0);
  compute(&As[(nt - 1) & 1][0], &Bs[(nt - 1) & 1][0]);
#undef STAGE_P

  const int cr = (lane >> 4) * 4;
  const int cc = lane & 15;
  #pragma unroll
  for (int j = 0; j < 4; ++j) {
    const int n = n0 + wc * 64 + j * 16 + cr;
    const float4 b4 = *reinterpret_cast<const float4*>(bias + n);
    #pragma unroll
    for (int i = 0; i < 4; ++i) {
      const int m = m0 + wr * 64 + i * 16 + cc;
      float4 r;
      r.x = acc[i][j][0] + b4.x;
      r.y = acc[i][j][1] + b4.y;
      r.z = acc[i][j][2] + b4.z;
      r.w = acc[i][j][3] + b4.w;
      *reinterpret_cast<float4*>(Cf + (size_t)m * N + n) = r;
    }
  }
}

// ---------- stripe attention + LePE, TWO windows per wave ----------
__global__ __launch_bounds__(256) void attn_lepe(
    const unsigned short* __restrict__ qkvp,
    const unsigned short* __restrict__ wlep,
    unsigned short* __restrict__ outp)
{
  const int gw   = (int)((blockIdx.x * 256 + threadIdx.x) >> 6);  // pair index
  const int lane = threadIdx.x & 63;
  const int half = gw >> 14;
  const int id   = gw & 16383;
  const int b    = id >> 11;
  const int n    = (id >> 8) & 7;
  int h0, w0;
  if (half == 0) { h0 = ((id >> 5) & 7) * 8; w0 = (id & 31) * 2; }
  else           { h0 = ((id >> 3) & 31) * 2; w0 = (id & 7) * 8; }
  const int baseA = qkv_idx(half, b, n, h0, w0);
  const int dWin  = (half == 0) ? 256 : 2048;
  const int baseB = baseA + dWin;

  // ---- QK^T for both windows: lane = (qr, kr) ----
  const int qr = lane >> 3, kr = lane & 7;
  const unsigned short* qA = qkvp + baseA + qr * 32;
  const unsigned short* kA = qkvp + 16777216 + baseA + kr * 32;
  float sA = 0.f, sB = 0.f;
  #pragma unroll
  for (int c = 0; c < 4; ++c) {
    const u32x4 qa = *reinterpret_cast<const u32x4*>(qA + c * 8);
    const u32x4 ka = *reinterpret_cast<const u32x4*>(kA + c * 8);
    const u32x4 qb = *reinterpret_cast<const u32x4*>(qA + dWin + c * 8);
    const u32x4 kb = *reinterpret_cast<const u32x4*>(kA + dWin + c * 8);
    #pragma unroll
    for (int e = 0; e < 4; ++e) {
      sA = __builtin_amdgcn_fdot2(bch2(qa[e]), bch2(ka[e]), sA, false);
      sB = __builtin_amdgcn_fdot2(bch2(qb[e]), bch2(kb[e]), sB, false);
    }
  }
  const float scl = 0.17677669529663687f;
  const float pA = __expf(sA * scl);
  const float pB = __expf(sB * scl);
  float denA = pA, denB = pB;
  denA += __shfl_xor(denA, 1); denA += __shfl_xor(denA, 2); denA += __shfl_xor(denA, 4);
  denB += __shfl_xor(denB, 1); denB += __shfl_xor(denB, 2); denB += __shfl_xor(denB, 4);
  const float aAv = pA * __builtin_amdgcn_rcpf(denA);
  const float aBv = pB * __builtin_amdgcn_rcpf(denB);
  const uint32_t adu = pkrtz_u32(aAv, aBv);   // lo = winA, hi = winB

  // ---- PV: lane = (qr2, win, dgrp); 16B vectors over 8 channels ----
  const int dgrp = lane & 3;
  const int win  = (lane >> 2) & 1;
  const int qr2  = lane >> 3;
  const int d0   = dgrp * 8;
  const int mybase = win ? baseB : baseA;
  const unsigned short* vwin = qkvp + 33554432 + mybase;

  half2v o01 = {0,0}, o23 = {0,0}, o45 = {0,0}, o67 = {0,0};
  #pragma unroll
  for (int k = 0; k < 8; ++k) {
    const uint32_t pairw = (uint32_t)__shfl((int)adu, qr2 * 8 + k);
    const half2v ph = bch2(pairw);
    const _Float16 av = win ? ph.y : ph.x;
    const half2v ak2 = {av, av};
    const u32x4 vv = *reinterpret_cast<const u32x4*>(vwin + k * 32 + d0);
    o01 += ak2 * bch2(vv[0]);
    o23 += ak2 * bch2(vv[1]);
    o45 += ak2 * bch2(vv[2]);
    o67 += ak2 * bch2(vv[3]);
  }

  // ---- LePE: depthwise 3x3 on v (zero-pad SAME) at this lane's pixel ----
  const int hq = (half == 0) ? (h0 + qr2) : (h0 + win);
  const int wq = (half == 0) ? (w0 + win) : (w0 + qr2);
  const unsigned short* vplane = qkvp + 33554432;
  const unsigned short* wl = wlep + half * 2304 + n * 32 + d0;
  half2v l01 = {0,0}, l23 = {0,0}, l45 = {0,0}, l67 = {0,0};
  #pragma unroll
  for (int dy = -1; dy <= 1; ++dy) {
    #pragma unroll
    for (int dx = -1; dx <= 1; ++dx) {
      const int hh = hq + dy, ww = wq + dx;
      u32x4 vv = {0u, 0u, 0u, 0u};
      if ((unsigned)hh < 64u && (unsigned)ww < 64u)
        vv = *reinterpret_cast<const u32x4*>(vplane + qkv_idx(half, b, n, hh, ww) + d0);
      const u32x4 wt = *reinterpret_cast<const u32x4*>(wl + ((dy + 1) * 3 + dx + 1) * 256);
      l01 += bch2(wt[0]) * bch2(vv[0]);
      l23 += bch2(wt[1]) * bch2(vv[1]);
      l45 += bch2(wt[2]) * bch2(vv[2]);
      l67 += bch2(wt[3]) * bch2(vv[3]);
    }
  }

  // ---- store token-major for GEMM2 (16B per lane) ----
  const int m = b * 4096 + hq * 64 + wq;
  const int chan0 = half * 256 + n * 32;
  u32x4 r;
  r[0] = __builtin_bit_cast(uint32_t, (half2v)(o01 + l01));
  r[1] = __builtin_bit_cast(uint32_t, (half2v)(o23 + l23));
  r[2] = __builtin_bit_cast(uint32_t, (half2v)(o45 + l45));
  r[3] = __builtin_bit_cast(uint32_t, (half2v)(o67 + l67));
  *reinterpret_cast<u32x4*>(outp + (size_t)m * 512 + chan0 + d0) = r;
}

// ---------- launch ----------
extern "C" void kernel_launch(void* const* d_in, const int* in_sizes, int n_in,
                              void* d_out, int out_size, void* d_ws, size_t ws_size,
                              hipStream_t stream) {
  const float* x      = (const float*)d_in[0];   // (8, 4096, 512)
  const float* w_qkv  = (const float*)d_in[1];   // (1536, 512)
  const float* w_proj = (const float*)d_in[2];   // (512, 512)
  const float* b_proj = (const float*)d_in[3];   // (512,)
  const float* lepe_h = (const float*)d_in[4];   // (3,3,1,256)
  const float* lepe_v = (const float*)d_in[5];   // (3,3,1,256)
  float* out = (float*)d_out;                    // (8, 4096, 512) f32

  char* ws = (char*)d_ws;
  unsigned short* qkv_p   = (unsigned short*)ws;                 // 96MB: q|k|v window-major
  unsigned short* ah      = (unsigned short*)(ws + 100663296);   // 32MB: attn_out f16
  unsigned short* wqkv_h  = (unsigned short*)(ws + 134217728);   // 1536*512 f16
  unsigned short* wproj_h = (unsigned short*)(ws + 135790592);   // 512*512 f16
  unsigned short* wlep_h  = (unsigned short*)(ws + 136314880);   // 2*9*256 f16

  // weight casts only (x-cast fused into gemm_qkv)
  cvt_f32_f16<<<768, 256, 0, stream>>>(w_qkv, wqkv_h, 196608);
  cvt_f32_f16<<<256, 256, 0, stream>>>(w_proj, wproj_h, 65536);
  cvt_f32_f16<<<3,   256, 0, stream>>>(lepe_h, wlep_h, 576);
  cvt_f32_f16<<<3,   256, 0, stream>>>(lepe_v, wlep_h + 2304, 576);

  // qkv = x @ w_qkv^T -> window-major f16 regions (A staged from f32 x)
  gemm_qkv<<<3072, 256, 0, stream>>>(x, wqkv_h, qkv_p);

  // stripe attention + LePE -> attn_out token-major
  attn_lepe<<<8192, 256, 0, stream>>>(qkv_p, wlep_h, ah);

  // out = attn_out @ w_proj^T + b_proj -> f32
  gemm_proj<<<1024, 256, 0, stream>>>(ah, wproj_h, out, b_proj);
}

// Round 12
// 185.629 us; speedup vs baseline: 1.0393x; 1.0072x over previous
//
#include <hip/hip_runtime.h>
#include <hip/hip_bf16.h>
#include <stdint.h>

// ---------- types ----------
typedef _Float16 half2v __attribute__((ext_vector_type(2)));
typedef _Float16 half8v __attribute__((ext_vector_type(8)));
typedef uint32_t u32x4  __attribute__((ext_vector_type(4)));
typedef float    f32x4  __attribute__((ext_vector_type(4)));

__device__ __forceinline__ unsigned short f2h(float f) {
  _Float16 h = (_Float16)f;
  return __builtin_bit_cast(unsigned short, h);
}
__device__ __forceinline__ half2v bch2(uint32_t u) {
  return __builtin_bit_cast(half2v, u);
}
__device__ __forceinline__ uint32_t pkrtz_u32(float a, float b) {
  return __builtin_bit_cast(uint32_t, __builtin_amdgcn_cvt_pkrtz(a, b));
}

// Window-major qkv layout. Element index (channel 0 of head n) for pixel (h,w),
// within one tensor's 32MB region (16M f16 elems; includes the half offset).
//  half 0 (horizontal stripes): [b][n][s=h>>3][w][qr=h&7][cc]
//  half 1 (vertical stripes):   [b][n][h][s=w>>3][qr=w&7][cc]
__device__ __forceinline__ int qkv_idx(int half, int b, int n, int h, int w) {
  int idx = half * 8388608 + (b * 8 + n) * 131072;
  idx += (half == 0) ? ((h >> 3) * 16384 + w * 256 + (h & 7) * 32)
                     : (h * 2048 + w * 32);
  return idx;
}

// async global->LDS, 16 bytes per lane. lbase must be wave-uniform.
#define GLOAD_LDS16(gsrc, lbase)                                          \
  __builtin_amdgcn_global_load_lds(                                       \
      (const __attribute__((address_space(1))) uint32_t*)(gsrc),          \
      (__attribute__((address_space(3))) uint32_t*)(lbase), 16, 0, 0)

// ---------- f32 -> f16 conversion (weights only; 4 elems/thread) ----------
__global__ __launch_bounds__(256) void cvt_f32_f16(const float* __restrict__ in,
                                                   unsigned short* __restrict__ out,
                                                   int n4) {
  int i = blockIdx.x * 256 + threadIdx.x;
  if (i >= n4) return;
  float4 f = reinterpret_cast<const float4*>(in)[i];
  ushort4 u;
  u.x = f2h(f.x); u.y = f2h(f.y); u.z = f2h(f.z); u.w = f2h(f.w);
  reinterpret_cast<ushort4*>(out)[i] = u;
}

// ---------- GEMM1: qkv = x(f32) @ w_qkv(f16)^T -> window-major f16 ----------
// Fused x-cast: A transported global(f32)->regs->cvt_pkrtz->ds_write into the
// R9-PROVEN f16 LDS layout (slot tid holds global chunk (tid&3)^((tid>>3)&3)
// of row tid>>2; rows +64 in upper half). Writes are lane-contiguous 16B
// (conflict-free); reads use the proven slot = kg^((lr>>1)&3) (0 conflicts).
// B staged via global_load_lds exactly as R9. Counted-vmcnt skeleton:
//   vmcnt(2): A(t) regs arrived -> cvt+ds_write buf[t&1]
//   issue A(t+1) 4 loads + B(t+1) 2 gload_lds -> vmcnt(6): B(t) in LDS
//   lgkmcnt(0) -> s_barrier -> compute(t) -> s_barrier.
// 1D grid, bijective XCD swizzle, n-fast in XCD chunk; operand-swapped epilogue.
__global__ __launch_bounds__(256) void gemm_qkv(
    const float* __restrict__ X,           // 32768 x 512 f32
    const unsigned short* __restrict__ B,  // 1536 x 512 f16
    unsigned short* __restrict__ Cq)
{
  constexpr int K = 512, N = 1536;
  __shared__ unsigned short Ah[2][128 * 32];   // 2 x 8KB (f16)
  __shared__ unsigned short Bh[2][128 * 32];   // 2 x 8KB
  const int tid  = threadIdx.x;
  const int gn   = N >> 7;                 // 12
  const int cpx  = gridDim.x >> 3;
  const int bid  = blockIdx.x;
  const int wgid = (bid & 7) * cpx + (bid >> 3);
  const int m0   = (wgid / gn) * 128;
  const int n0   = (wgid % gn) * 128;
  const int wave = tid >> 6, lane = tid & 63;
  const int wr = wave >> 1, wc = wave & 1;
  // staging coords (R9 formulas): row sr, pre-swizzled element col sc
  const int sr = tid >> 2;
  const int sc = ((tid & 3) ^ ((tid >> 3) & 3)) * 8;
  const size_t aBase0 = (size_t)(m0 + sr) * K + sc;        // f32 elements
  const size_t aBase1 = (size_t)(m0 + 64 + sr) * K + sc;
  const size_t bBase0 = (size_t)(n0 + sr) * K + sc;        // f16 elements
  const size_t bBase1 = (size_t)(n0 + 64 + sr) * K + sc;
  char* ldsB = (char*)(&Bh[0][0]) + (tid & ~63) * 16;

  float4 a00, a01, a10, a11;   // A(t) in regs: row sr (2x16B) + row sr+64

#define LOADA(kt)                                                         \
  do {                                                                    \
    a00 = *reinterpret_cast<const float4*>(X + aBase0 + (kt));            \
    a01 = *reinterpret_cast<const float4*>(X + aBase0 + (kt) + 4);        \
    a10 = *reinterpret_cast<const float4*>(X + aBase1 + (kt));            \
    a11 = *reinterpret_cast<const float4*>(X + aBase1 + (kt) + 4);        \
  } while (0)

#define GLOADB(bsel, kt)                                                  \
  do {                                                                    \
    GLOAD_LDS16(B + bBase0 + (kt), ldsB + (bsel) * 8192);                 \
    GLOAD_LDS16(B + bBase1 + (kt), ldsB + (bsel) * 8192 + 4096);          \
  } while (0)

#define WRITEA(abuf)                                                      \
  do {                                                                    \
    u32x4 w0, w1;                                                         \
    w0[0] = pkrtz_u32(a00.x, a00.y); w0[1] = pkrtz_u32(a00.z, a00.w);     \
    w0[2] = pkrtz_u32(a01.x, a01.y); w0[3] = pkrtz_u32(a01.z, a01.w);     \
    w1[0] = pkrtz_u32(a10.x, a10.y); w1[1] = pkrtz_u32(a10.z, a10.w);     \
    w1[2] = pkrtz_u32(a11.x, a11.y); w1[3] = pkrtz_u32(a11.z, a11.w);     \
    *reinterpret_cast<u32x4*>((abuf) + tid * 8)        = w0;              \
    *reinterpret_cast<u32x4*>((abuf) + tid * 8 + 2048) = w1;              \
  } while (0)

  // prologue: tile 0 in flight
  LOADA(0);
  GLOADB(0, 0);

  f32x4 acc[4][4];
  const f32x4 zero = {0.f, 0.f, 0.f, 0.f};
  #pragma unroll
  for (int i = 0; i < 4; ++i)
    #pragma unroll
    for (int j = 0; j < 4; ++j) acc[i][j] = zero;

  const int lr   = lane & 15;
  const int slot = (lane >> 4) ^ ((lr >> 1) & 3);   // proven swizzled slot

  auto compute = [&](const unsigned short* Asb, const unsigned short* Bsb) {
    half8v af[4], bfr[4];
    #pragma unroll
    for (int i = 0; i < 4; ++i)
      af[i] = *reinterpret_cast<const half8v*>(Asb + (wr * 64 + i * 16 + lr) * 32 + slot * 8);
    #pragma unroll
    for (int j = 0; j < 4; ++j)
      bfr[j] = *reinterpret_cast<const half8v*>(Bsb + (wc * 64 + j * 16 + lr) * 32 + slot * 8);
    __builtin_amdgcn_s_setprio(1);
    #pragma unroll
    for (int i = 0; i < 4; ++i)
      #pragma unroll
      for (int j = 0; j < 4; ++j)
        acc[i][j] = __builtin_amdgcn_mfma_f32_16x16x32_f16(bfr[j], af[i], acc[i][j], 0, 0, 0);
    __builtin_amdgcn_s_setprio(0);
  };

  const int nt = K >> 5;   // 16
  for (int t = 0; t < nt; ++t) {
    unsigned short* abuf = (t & 1) ? &Ah[1][0] : &Ah[0][0];
    const unsigned short* bbuf = (t & 1) ? &Bh[1][0] : &Bh[0][0];
    asm volatile("s_waitcnt vmcnt(2)" ::: "memory");  // A(t) regs arrived
    WRITEA(abuf);                                      // cvt + 2 ds_write
    if (t + 1 < nt) {
      LOADA((t + 1) * 32);                             // reuse regs (WAR ok:
      GLOADB((t + 1) & 1, (t + 1) * 32);               //  ds_write issued)
      asm volatile("s_waitcnt vmcnt(6)" ::: "memory"); // B(t) landed in LDS
    } else {
      asm volatile("s_waitcnt vmcnt(0)" ::: "memory");
    }
    asm volatile("s_waitcnt lgkmcnt(0)" ::: "memory"); // my A-writes done
    __builtin_amdgcn_s_barrier();                      // tile t visible
    __builtin_amdgcn_sched_barrier(0);
    compute(abuf, bbuf);
    __builtin_amdgcn_s_barrier();                      // all done with buf t
    __builtin_amdgcn_sched_barrier(0);
  }
#undef LOADA
#undef GLOADB
#undef WRITEA

  // D layout (operand-swapped): row(n) = (lane>>4)*4 + e, col(m) = lane&15
  const int cr = (lane >> 4) * 4;
  const int cc = lane & 15;
  const int mb   = m0 + wr * 64;
  const int btok = mb >> 12;
  const int htok = (mb >> 6) & 63;
  #pragma unroll
  for (int j = 0; j < 4; ++j) {
    const int nb    = n0 + wc * 64 + j * 16 + cr;  // 4 contiguous channels
    const int tq    = nb >> 9;
    const int halfc = (nb >> 8) & 1;
    const int nn    = (nb & 255) >> 5;
    const int ch4   = nb & 31;
    int base = tq * 16777216 + halfc * 8388608 + (btok * 8 + nn) * 131072 + ch4;
    base += halfc ? (htok * 2048) : ((htok >> 3) * 16384 + (htok & 7) * 32);
    const int wstride = halfc ? 32 : 256;
    #pragma unroll
    for (int i = 0; i < 4; ++i) {
      const int wpix = i * 16 + cc;
      uint2 r;
      r.x = pkrtz_u32(acc[i][j][0], acc[i][j][1]);
      r.y = pkrtz_u32(acc[i][j][2], acc[i][j][3]);
      *reinterpret_cast<uint2*>(Cq + base + wpix * wstride) = r;
    }
  }
}

// ---------- GEMM2: out = attn_out(f16) @ w_proj(f16)^T + bias -> f32 ----------
// Verbatim R9 MODE-0 path (proven 128x128, gload_lds, counted vmcnt(4)).
__global__ __launch_bounds__(256) void gemm_proj(
    const unsigned short* __restrict__ A,
    const unsigned short* __restrict__ B,
    float* __restrict__ Cf,
    const float* __restrict__ bias)
{
  constexpr int K = 512, N = 512;
  __shared__ unsigned short As[2][128 * 32];
  __shared__ unsigned short Bs[2][128 * 32];
  const int tid  = threadIdx.x;
  const int gn   = N >> 7;                 // 4
  const int cpx  = gridDim.x >> 3;
  const int bid  = blockIdx.x;
  const int wgid = (bid & 7) * cpx + (bid >> 3);
  const int m0   = (wgid / gn) * 128;
  const int n0   = (wgid % gn) * 128;
  const int wave = tid >> 6, lane = tid & 63;
  const int wr = wave >> 1, wc = wave & 1;
  const int sr = tid >> 2;
  const int sc = ((tid & 3) ^ ((tid >> 3) & 3)) * 8;
  const size_t aBase0 = (size_t)(m0 + sr) * K + sc;
  const size_t aBase1 = (size_t)(m0 + 64 + sr) * K + sc;
  const size_t bBase0 = (size_t)(n0 + sr) * K + sc;
  const size_t bBase1 = (size_t)(n0 + 64 + sr) * K + sc;
  char* ldsA = (char*)(&As[0][0]) + (tid & ~63) * 16;
  char* ldsB = (char*)(&Bs[0][0]) + (tid & ~63) * 16;

#define STAGE_P(bsel, kofs)                                        \
  do {                                                             \
    GLOAD_LDS16(A + aBase0 + (kofs), ldsA + (bsel) * 8192);        \
    GLOAD_LDS16(A + aBase1 + (kofs), ldsA + (bsel) * 8192 + 4096); \
    GLOAD_LDS16(B + bBase0 + (kofs), ldsB + (bsel) * 8192);        \
    GLOAD_LDS16(B + bBase1 + (kofs), ldsB + (bsel) * 8192 + 4096); \
  } while (0)

  STAGE_P(0, 0);

  f32x4 acc[4][4];
  const f32x4 zero = {0.f, 0.f, 0.f, 0.f};
  #pragma unroll
  for (int i = 0; i < 4; ++i)
    #pragma unroll
    for (int j = 0; j < 4; ++j) acc[i][j] = zero;

  const int lr   = lane & 15;
  const int slot = (lane >> 4) ^ ((lr >> 1) & 3);

  auto compute = [&](const unsigned short* Asb, const unsigned short* Bsb) {
    half8v af[4], bfr[4];
    #pragma unroll
    for (int i = 0; i < 4; ++i)
      af[i] = *reinterpret_cast<const half8v*>(Asb + (wr * 64 + i * 16 + lr) * 32 + slot * 8);
    #pragma unroll
    for (int j = 0; j < 4; ++j)
      bfr[j] = *reinterpret_cast<const half8v*>(Bsb + (wc * 64 + j * 16 + lr) * 32 + slot * 8);
    __builtin_amdgcn_s_setprio(1);
    #pragma unroll
    for (int i = 0; i < 4; ++i)
      #pragma unroll
      for (int j = 0; j < 4; ++j)
        acc[i][j] = __builtin_amdgcn_mfma_f32_16x16x32_f16(bfr[j], af[i], acc[i][j], 0, 0, 0);
    __builtin_amdgcn_s_setprio(0);
  };

  const int nt = K >> 5;
  for (int t = 0; t < nt - 1; ++t) {
    STAGE_P((t + 1) & 1, (t + 1) * 32);
    asm volatile("s_waitcnt vmcnt(4)" ::: "memory");
    __builtin_amdgcn_s_barrier();
    __builtin_amdgcn_sched_barrier(0);
    compute(&As[t & 1][0], &Bs[t & 1][0]);
    __builtin_amdgcn_s_barrier();
    __builtin_amdgcn_sched_barrier(0);
  }
  asm volatile("s_waitcnt vmcnt(0)" ::: "memory");
  __builtin_amdgcn_s_barrier();
  __builtin_amdgcn_sched_barrier(0);
  compute(&As[(nt - 1) & 1][0], &Bs[(nt - 1) & 1][0]);
#undef STAGE_P

  const int cr = (lane >> 4) * 4;
  const int cc = lane & 15;
  #pragma unroll
  for (int j = 0; j < 4; ++j) {
    const int n = n0 + wc * 64 + j * 16 + cr;
    const float4 b4 = *reinterpret_cast<const float4*>(bias + n);
    #pragma unroll
    for (int i = 0; i < 4; ++i) {
      const int m = m0 + wr * 64 + i * 16 + cc;
      float4 r;
      r.x = acc[i][j][0] + b4.x;
      r.y = acc[i][j][1] + b4.y;
      r.z = acc[i][j][2] + b4.z;
      r.w = acc[i][j][3] + b4.w;
      *reinterpret_cast<float4*>(Cf + (size_t)m * N + n) = r;
    }
  }
}

// ---------- stripe attention + LePE, TWO windows per wave ----------
__global__ __launch_bounds__(256) void attn_lepe(
    const unsigned short* __restrict__ qkvp,
    const unsigned short* __restrict__ wlep,
    unsigned short* __restrict__ outp)
{
  const int gw   = (int)((blockIdx.x * 256 + threadIdx.x) >> 6);  // pair index
  const int lane = threadIdx.x & 63;
  const int half = gw >> 14;
  const int id   = gw & 16383;
  const int b    = id >> 11;
  const int n    = (id >> 8) & 7;
  int h0, w0;
  if (half == 0) { h0 = ((id >> 5) & 7) * 8; w0 = (id & 31) * 2; }
  else           { h0 = ((id >> 3) & 31) * 2; w0 = (id & 7) * 8; }
  const int baseA = qkv_idx(half, b, n, h0, w0);
  const int dWin  = (half == 0) ? 256 : 2048;
  const int baseB = baseA + dWin;

  // ---- QK^T for both windows: lane = (qr, kr) ----
  const int qr = lane >> 3, kr = lane & 7;
  const unsigned short* qA = qkvp + baseA + qr * 32;
  const unsigned short* kA = qkvp + 16777216 + baseA + kr * 32;
  float sA = 0.f, sB = 0.f;
  #pragma unroll
  for (int c = 0; c < 4; ++c) {
    const u32x4 qa = *reinterpret_cast<const u32x4*>(qA + c * 8);
    const u32x4 ka = *reinterpret_cast<const u32x4*>(kA + c * 8);
    const u32x4 qb = *reinterpret_cast<const u32x4*>(qA + dWin + c * 8);
    const u32x4 kb = *reinterpret_cast<const u32x4*>(kA + dWin + c * 8);
    #pragma unroll
    for (int e = 0; e < 4; ++e) {
      sA = __builtin_amdgcn_fdot2(bch2(qa[e]), bch2(ka[e]), sA, false);
      sB = __builtin_amdgcn_fdot2(bch2(qb[e]), bch2(kb[e]), sB, false);
    }
  }
  const float scl = 0.17677669529663687f;
  const float pA = __expf(sA * scl);
  const float pB = __expf(sB * scl);
  float denA = pA, denB = pB;
  denA += __shfl_xor(denA, 1); denA += __shfl_xor(denA, 2); denA += __shfl_xor(denA, 4);
  denB += __shfl_xor(denB, 1); denB += __shfl_xor(denB, 2); denB += __shfl_xor(denB, 4);
  const float aAv = pA * __builtin_amdgcn_rcpf(denA);
  const float aBv = pB * __builtin_amdgcn_rcpf(denB);
  const uint32_t adu = pkrtz_u32(aAv, aBv);   // lo = winA, hi = winB

  // ---- PV: lane = (qr2, win, dgrp); 16B vectors over 8 channels ----
  const int dgrp = lane & 3;
  const int win  = (lane >> 2) & 1;
  const int qr2  = lane >> 3;
  const int d0   = dgrp * 8;
  const int mybase = win ? baseB : baseA;
  const unsigned short* vwin = qkvp + 33554432 + mybase;

  half2v o01 = {0,0}, o23 = {0,0}, o45 = {0,0}, o67 = {0,0};
  #pragma unroll
  for (int k = 0; k < 8; ++k) {
    const uint32_t pairw = (uint32_t)__shfl((int)adu, qr2 * 8 + k);
    const half2v ph = bch2(pairw);
    const _Float16 av = win ? ph.y : ph.x;
    const half2v ak2 = {av, av};
    const u32x4 vv = *reinterpret_cast<const u32x4*>(vwin + k * 32 + d0);
    o01 += ak2 * bch2(vv[0]);
    o23 += ak2 * bch2(vv[1]);
    o45 += ak2 * bch2(vv[2]);
    o67 += ak2 * bch2(vv[3]);
  }

  // ---- LePE: depthwise 3x3 on v (zero-pad SAME) at this lane's pixel ----
  const int hq = (half == 0) ? (h0 + qr2) : (h0 + win);
  const int wq = (half == 0) ? (w0 + win) : (w0 + qr2);
  const unsigned short* vplane = qkvp + 33554432;
  const unsigned short* wl = wlep + half * 2304 + n * 32 + d0;
  half2v l01 = {0,0}, l23 = {0,0}, l45 = {0,0}, l67 = {0,0};
  #pragma unroll
  for (int dy = -1; dy <= 1; ++dy) {
    #pragma unroll
    for (int dx = -1; dx <= 1; ++dx) {
      const int hh = hq + dy, ww = wq + dx;
      u32x4 vv = {0u, 0u, 0u, 0u};
      if ((unsigned)hh < 64u && (unsigned)ww < 64u)
        vv = *reinterpret_cast<const u32x4*>(vplane + qkv_idx(half, b, n, hh, ww) + d0);
      const u32x4 wt = *reinterpret_cast<const u32x4*>(wl + ((dy + 1) * 3 + dx + 1) * 256);
      l01 += bch2(wt[0]) * bch2(vv[0]);
      l23 += bch2(wt[1]) * bch2(vv[1]);
      l45 += bch2(wt[2]) * bch2(vv[2]);
      l67 += bch2(wt[3]) * bch2(vv[3]);
    }
  }

  // ---- store token-major for GEMM2 (16B per lane) ----
  const int m = b * 4096 + hq * 64 + wq;
  const int chan0 = half * 256 + n * 32;
  u32x4 r;
  r[0] = __builtin_bit_cast(uint32_t, (half2v)(o01 + l01));
  r[1] = __builtin_bit_cast(uint32_t, (half2v)(o23 + l23));
  r[2] = __builtin_bit_cast(uint32_t, (half2v)(o45 + l45));
  r[3] = __builtin_bit_cast(uint32_t, (half2v)(o67 + l67));
  *reinterpret_cast<u32x4*>(outp + (size_t)m * 512 + chan0 + d0) = r;
}

// ---------- launch ----------
extern "C" void kernel_launch(void* const* d_in, const int* in_sizes, int n_in,
                              void* d_out, int out_size, void* d_ws, size_t ws_size,
                              hipStream_t stream) {
  const float* x      = (const float*)d_in[0];   // (8, 4096, 512)
  const float* w_qkv  = (const float*)d_in[1];   // (1536, 512)
  const float* w_proj = (const float*)d_in[2];   // (512, 512)
  const float* b_proj = (const float*)d_in[3];   // (512,)
  const float* lepe_h = (const float*)d_in[4];   // (3,3,1,256)
  const float* lepe_v = (const float*)d_in[5];   // (3,3,1,256)
  float* out = (float*)d_out;                    // (8, 4096, 512) f32

  char* ws = (char*)d_ws;
  unsigned short* qkv_p   = (unsigned short*)ws;                 // 96MB: q|k|v window-major
  unsigned short* ah      = (unsigned short*)(ws + 100663296);   // 32MB: attn_out f16
  unsigned short* wqkv_h  = (unsigned short*)(ws + 134217728);   // 1536*512 f16
  unsigned short* wproj_h = (unsigned short*)(ws + 135790592);   // 512*512 f16
  unsigned short* wlep_h  = (unsigned short*)(ws + 136314880);   // 2*9*256 f16

  // weight casts only (x-cast fused into gemm_qkv)
  cvt_f32_f16<<<768, 256, 0, stream>>>(w_qkv, wqkv_h, 196608);
  cvt_f32_f16<<<256, 256, 0, stream>>>(w_proj, wproj_h, 65536);
  cvt_f32_f16<<<3,   256, 0, stream>>>(lepe_h, wlep_h, 576);
  cvt_f32_f16<<<3,   256, 0, stream>>>(lepe_v, wlep_h + 2304, 576);

  // qkv = x @ w_qkv^T -> window-major f16 regions (A reg-staged from f32 x)
  gemm_qkv<<<3072, 256, 0, stream>>>(x, wqkv_h, qkv_p);

  // stripe attention + LePE -> attn_out token-major
  attn_lepe<<<8192, 256, 0, stream>>>(qkv_p, wlep_h, ah);

  // out = attn_out @ w_proj^T + b_proj -> f32
  gemm_proj<<<1024, 256, 0, stream>>>(ah, wproj_h, out, b_proj);
}

// Round 13
// 175.563 us; speedup vs baseline: 1.0989x; 1.0573x over previous
//
#include <hip/hip_runtime.h>
#include <hip/hip_bf16.h>
#include <stdint.h>

// ---------- types ----------
typedef _Float16 half2v __attribute__((ext_vector_type(2)));
typedef _Float16 half8v __attribute__((ext_vector_type(8)));
typedef uint32_t u32x4  __attribute__((ext_vector_type(4)));
typedef float    f32x4  __attribute__((ext_vector_type(4)));

__device__ __forceinline__ unsigned short f2h(float f) {
  _Float16 h = (_Float16)f;
  return __builtin_bit_cast(unsigned short, h);
}
__device__ __forceinline__ half2v bch2(uint32_t u) {
  return __builtin_bit_cast(half2v, u);
}
__device__ __forceinline__ uint32_t pkrtz_u32(float a, float b) {
  return __builtin_bit_cast(uint32_t, __builtin_amdgcn_cvt_pkrtz(a, b));
}

// Window-major qkv layout (channel 0 of head n, pixel (h,w)).
__device__ __forceinline__ int qkv_idx(int half, int b, int n, int h, int w) {
  int idx = half * 8388608 + (b * 8 + n) * 131072;
  idx += (half == 0) ? ((h >> 3) * 16384 + w * 256 + (h & 7) * 32)
                     : (h * 2048 + w * 32);
  return idx;
}

// async global->LDS, 16 bytes per lane. lbase = wave-uniform base.
#define GLOAD_LDS16(gsrc, lbase)                                          \
  __builtin_amdgcn_global_load_lds(                                       \
      (const __attribute__((address_space(1))) uint32_t*)(gsrc),          \
      (__attribute__((address_space(3))) uint32_t*)(lbase), 16, 0, 0)

// ---------- f32 -> f16 conversion (4 elems/thread) ----------
__global__ __launch_bounds__(256) void cvt_f32_f16(const float* __restrict__ in,
                                                   unsigned short* __restrict__ out,
                                                   int n4) {
  int i = blockIdx.x * 256 + threadIdx.x;
  if (i >= n4) return;
  float4 f = reinterpret_cast<const float4*>(in)[i];
  ushort4 u;
  u.x = f2h(f.x); u.y = f2h(f.y); u.z = f2h(f.z); u.w = f2h(f.w);
  reinterpret_cast<ushort4*>(out)[i] = u;
}

// ---------- 8-phase 256^2 f16 GEMM: C[m,n] = sum_k A[m,k]*B[n,k] ----------
// 512 thr = 8 waves (2M x 4N), wave tile 128x64, MFMA 16x16x32 (operand-swap).
// LDS 128KB: 2 K-tile buffers (BK=64) x (A 32KB + B 32KB).
// 8 phases / 2 K-tiles; phase = {ds_read subtile | stage | (vmcnt p4/p8) ->
// barrier -> 16 MFMA -> barrier}. Stage slots p1/p4/p5/p8, each issued after
// the bar2 following the last read of the space it overwrites, and landed
// (counted vmcnt(4)) before the boundary preceding its first read.
// Chunk-XOR LDS swizzle: LDS[r][slot] = global chunk slot^(r&7) (pre-swizzled
// source; read slot = (ks*4+kg)^(lr&7)); 2 lanes/bank per 16-lane group.
// MODE 0: f32 out + bias token-major. MODE 1: f16 scatter to qkv windows.
template<int MODE>
__global__ __launch_bounds__(512, 2) void gemm8(
    const unsigned short* __restrict__ A,
    const unsigned short* __restrict__ Bm,
    unsigned short* __restrict__ Cq,
    float* __restrict__ Cf,
    const float* __restrict__ bias,
    int M, int N)
{
  constexpr int K = 512;
  constexpr int NIT = 4;                    // K / 128
  __shared__ unsigned short As[2][256 * 64];   // 2 x 32KB
  __shared__ unsigned short Bs[2][256 * 64];   // 2 x 32KB
  const int tid  = threadIdx.x;
  const int gn   = N >> 8;
  const int cpx  = gridDim.x >> 3;
  const int bid  = blockIdx.x;
  const int wgid = (bid & 7) * cpx + (bid >> 3);   // bijective (grid%8==0)
  const int m0   = (wgid / gn) * 256;
  const int n0   = (wgid % gn) * 256;
  const int wave = tid >> 6, lane = tid & 63;
  const int wr  = wave >> 2;        // 0..1 (128 M-rows)
  const int wcn = wave & 3;         // 0..3 (64 N-cols)

  // staging: unit u covers rows u*64+(tid>>3); slot tid&7 <- global chunk slot^(row&7)
  const int srow = tid >> 3;
  const int schk = ((tid & 7) ^ (srow & 7)) * 8;
  const size_t aSrc = (size_t)(m0 + srow) * K + schk;
  const size_t bSrc = (size_t)(n0 + srow) * K + schk;
  char* ldsA = (char*)(&As[0][0]) + (tid & ~63) * 16;
  char* ldsB = (char*)(&Bs[0][0]) + (tid & ~63) * 16;

#define STAGE_A8(b, kt)                                                     \
  do {                                                                      \
    GLOAD_LDS16(A + aSrc + (size_t)(kt) * 64,             ldsA + (b) * 32768);         \
    GLOAD_LDS16(A + aSrc + (size_t)64 * K + (kt) * 64,    ldsA + (b) * 32768 + 8192);  \
    GLOAD_LDS16(A + aSrc + (size_t)128 * K + (kt) * 64,   ldsA + (b) * 32768 + 16384); \
    GLOAD_LDS16(A + aSrc + (size_t)192 * K + (kt) * 64,   ldsA + (b) * 32768 + 24576); \
  } while (0)
#define STAGE_B8(b, kt)                                                     \
  do {                                                                      \
    GLOAD_LDS16(Bm + bSrc + (size_t)(kt) * 64,            ldsB + (b) * 32768);         \
    GLOAD_LDS16(Bm + bSrc + (size_t)64 * K + (kt) * 64,   ldsB + (b) * 32768 + 8192);  \
    GLOAD_LDS16(Bm + bSrc + (size_t)128 * K + (kt) * 64,  ldsB + (b) * 32768 + 16384); \
    GLOAD_LDS16(Bm + bSrc + (size_t)192 * K + (kt) * 64,  ldsB + (b) * 32768 + 24576); \
  } while (0)
#define BARS                                                                \
  __builtin_amdgcn_s_barrier();                                             \
  __builtin_amdgcn_sched_barrier(0)

  // prologue: tile0 (buf0) + tile1 B; tile0 guaranteed, tile1-B in flight
  STAGE_A8(0, 0);
  STAGE_B8(0, 0);
  STAGE_B8(1, 1);

  f32x4 acc[8][4];
  const f32x4 zero = {0.f, 0.f, 0.f, 0.f};
  #pragma unroll
  for (int i = 0; i < 8; ++i)
    #pragma unroll
    for (int j = 0; j < 4; ++j) acc[i][j] = zero;

  const int lr  = lane & 15;
  const int kg  = lane >> 4;
  const int ck0 = kg ^ (lr & 7);            // k-step0 slot; k-step1 = ck0^4

  asm volatile("s_waitcnt vmcnt(4)" ::: "memory");
  BARS;

#define LD_AF(buf, mg, ks)                                                  \
  do {                                                                      \
    const unsigned short* ap = &As[buf][0] +                                \
        (wr * 128 + (mg) * 64 + lr) * 64 + (((ks) ? (ck0 ^ 4) : ck0)) * 8;  \
    af[0] = *(const half8v*)(ap);                                           \
    af[1] = *(const half8v*)(ap + 1024);                                    \
    af[2] = *(const half8v*)(ap + 2048);                                    \
    af[3] = *(const half8v*)(ap + 3072);                                    \
  } while (0)
#define LD_BF(buf, ks)                                                      \
  do {                                                                      \
    const unsigned short* bp = &Bs[buf][0] +                                \
        (wcn * 64 + lr) * 64 + (((ks) ? (ck0 ^ 4) : ck0)) * 8;              \
    bf[0] = *(const half8v*)(bp);                                           \
    bf[1] = *(const half8v*)(bp + 1024);                                    \
    bf[2] = *(const half8v*)(bp + 2048);                                    \
    bf[3] = *(const half8v*)(bp + 3072);                                    \
  } while (0)
#define MROW(mg, i)                                                         \
  acc[(mg)*4+(i)][0] = __builtin_amdgcn_mfma_f32_16x16x32_f16(bf[0], af[i], acc[(mg)*4+(i)][0], 0, 0, 0); \
  acc[(mg)*4+(i)][1] = __builtin_amdgcn_mfma_f32_16x16x32_f16(bf[1], af[i], acc[(mg)*4+(i)][1], 0, 0, 0); \
  acc[(mg)*4+(i)][2] = __builtin_amdgcn_mfma_f32_16x16x32_f16(bf[2], af[i], acc[(mg)*4+(i)][2], 0, 0, 0); \
  acc[(mg)*4+(i)][3] = __builtin_amdgcn_mfma_f32_16x16x32_f16(bf[3], af[i], acc[(mg)*4+(i)][3], 0, 0, 0);
#define MFMA16(mg)                                                          \
  do {                                                                      \
    __builtin_amdgcn_s_setprio(1);                                          \
    MROW(mg, 0); MROW(mg, 1); MROW(mg, 2); MROW(mg, 3);                     \
    __builtin_amdgcn_s_setprio(0);                                          \
  } while (0)

  for (int it2 = 0; it2 < NIT; ++it2) {
    const bool more = (it2 + 1 < NIT);
    const int keven = 2 * it2;
    half8v af[4], bf[4];
    // p1: buf0 k0 mg0; stage A(odd tile)->buf1
    LD_BF(0, 0); LD_AF(0, 0, 0);
    STAGE_A8(1, keven + 1);
    BARS;
    MFMA16(0);
    BARS;
    // p2: buf0 k0 mg1 (bf reused)
    LD_AF(0, 1, 0);
    BARS;
    MFMA16(1);
    BARS;
    // p3: buf0 k1 mg0
    LD_BF(0, 1); LD_AF(0, 0, 1);
    BARS;
    MFMA16(0);
    BARS;
    // p4: buf0 k1 mg1; stage B(next even)->buf0 (B space dead since p3);
    // counted vmcnt: odd tile (B@p8-prev, A@p1) fully landed.
    LD_AF(0, 1, 1);
    if (more) {
      STAGE_B8(0, keven + 2);
      asm volatile("s_waitcnt vmcnt(4)" ::: "memory");
    } else {
      asm volatile("s_waitcnt vmcnt(0)" ::: "memory");
    }
    BARS;
    MFMA16(1);
    BARS;
    // p5: buf1 k0 mg0; stage A(next even)->buf0 (A space dead since p4)
    LD_BF(1, 0); LD_AF(1, 0, 0);
    if (more) STAGE_A8(0, keven + 2);
    BARS;
    MFMA16(0);
    BARS;
    // p6: buf1 k0 mg1
    LD_AF(1, 1, 0);
    BARS;
    MFMA16(1);
    BARS;
    // p7: buf1 k1 mg0
    LD_BF(1, 1); LD_AF(1, 0, 1);
    BARS;
    MFMA16(0);
    BARS;
    // p8: buf1 k1 mg1; stage B(next odd)->buf1 (B space dead since p7);
    // counted vmcnt: next-even tile (B@p4, A@p5) fully landed.
    LD_AF(1, 1, 1);
    if (more) {
      STAGE_B8(1, keven + 3);
      asm volatile("s_waitcnt vmcnt(4)" ::: "memory");
    }
    BARS;
    MFMA16(1);
    BARS;
  }
#undef STAGE_A8
#undef STAGE_B8
#undef LD_AF
#undef LD_BF
#undef MROW
#undef MFMA16
#undef BARS

  // D layout (operand-swapped): row(n) = (lane>>4)*4 + e, col(m) = lane&15
  const int cr = (lane >> 4) * 4;   // channel offset (4 contiguous)
  const int cc = lane & 15;         // token offset

  if constexpr (MODE == 0) {
    #pragma unroll
    for (int j = 0; j < 4; ++j) {
      const int n = n0 + wcn * 64 + j * 16 + cr;
      const float4 b4 = *reinterpret_cast<const float4*>(bias + n);
      #pragma unroll
      for (int i = 0; i < 8; ++i) {
        const int m = m0 + wr * 128 + i * 16 + cc;
        float4 r;
        r.x = acc[i][j][0] + b4.x;
        r.y = acc[i][j][1] + b4.y;
        r.z = acc[i][j][2] + b4.z;
        r.w = acc[i][j][3] + b4.w;
        *reinterpret_cast<float4*>(Cf + (size_t)m * N + n) = r;
      }
    }
  } else {
    const int mb   = m0 + wr * 128;   // token base (wave-uniform, 128-aligned)
    const int btok = mb >> 12;
    const int hr0  = (mb >> 6) & 63;  // wave spans h-rows hr0, hr0+1
    #pragma unroll
    for (int j = 0; j < 4; ++j) {
      const int nb    = n0 + wcn * 64 + j * 16 + cr;  // 4 contiguous channels
      const int tq    = nb >> 9;                      // 0=q 1=k 2=v
      const int halfc = (nb >> 8) & 1;
      const int nn    = (nb & 255) >> 5;
      const int ch4   = nb & 31;
      const int headbase = tq * 16777216 + halfc * 8388608 +
                           (btok * 8 + nn) * 131072 + ch4;
      #pragma unroll
      for (int i = 0; i < 8; ++i) {
        const int hrow = hr0 + (i >> 2);
        const int wpix = (i & 3) * 16 + cc;
        const int off = halfc ? (hrow * 2048 + wpix * 32)
                              : ((hrow >> 3) * 16384 + wpix * 256 + (hrow & 7) * 32);
        uint2 r;
        r.x = pkrtz_u32(acc[i][j][0], acc[i][j][1]);
        r.y = pkrtz_u32(acc[i][j][2], acc[i][j][3]);
        *reinterpret_cast<uint2*>(Cq + headbase + off) = r;
      }
    }
  }
}

// ---------- stripe attention + LePE, TWO windows per wave ----------
__global__ __launch_bounds__(256) void attn_lepe(
    const unsigned short* __restrict__ qkvp,
    const unsigned short* __restrict__ wlep,
    unsigned short* __restrict__ outp)
{
  const int gw   = (int)((blockIdx.x * 256 + threadIdx.x) >> 6);  // pair index
  const int lane = threadIdx.x & 63;
  const int half = gw >> 14;
  const int id   = gw & 16383;
  const int b    = id >> 11;
  const int n    = (id >> 8) & 7;
  int h0, w0;
  if (half == 0) { h0 = ((id >> 5) & 7) * 8; w0 = (id & 31) * 2; }
  else           { h0 = ((id >> 3) & 31) * 2; w0 = (id & 7) * 8; }
  const int baseA = qkv_idx(half, b, n, h0, w0);
  const int dWin  = (half == 0) ? 256 : 2048;
  const int baseB = baseA + dWin;

  // ---- QK^T for both windows: lane = (qr, kr) ----
  const int qr = lane >> 3, kr = lane & 7;
  const unsigned short* qA = qkvp + baseA + qr * 32;
  const unsigned short* kA = qkvp + 16777216 + baseA + kr * 32;
  float sA = 0.f, sB = 0.f;
  #pragma unroll
  for (int c = 0; c < 4; ++c) {
    const u32x4 qa = *reinterpret_cast<const u32x4*>(qA + c * 8);
    const u32x4 ka = *reinterpret_cast<const u32x4*>(kA + c * 8);
    const u32x4 qb = *reinterpret_cast<const u32x4*>(qA + dWin + c * 8);
    const u32x4 kb = *reinterpret_cast<const u32x4*>(kA + dWin + c * 8);
    #pragma unroll
    for (int e = 0; e < 4; ++e) {
      sA = __builtin_amdgcn_fdot2(bch2(qa[e]), bch2(ka[e]), sA, false);
      sB = __builtin_amdgcn_fdot2(bch2(qb[e]), bch2(kb[e]), sB, false);
    }
  }
  const float scl = 0.17677669529663687f;
  const float pA = __expf(sA * scl);
  const float pB = __expf(sB * scl);
  float denA = pA, denB = pB;
  denA += __shfl_xor(denA, 1); denA += __shfl_xor(denA, 2); denA += __shfl_xor(denA, 4);
  denB += __shfl_xor(denB, 1); denB += __shfl_xor(denB, 2); denB += __shfl_xor(denB, 4);
  const float aAv = pA * __builtin_amdgcn_rcpf(denA);
  const float aBv = pB * __builtin_amdgcn_rcpf(denB);
  const uint32_t adu = pkrtz_u32(aAv, aBv);   // lo = winA, hi = winB

  // ---- PV: lane = (qr2, win, dgrp); 16B vectors over 8 channels ----
  const int dgrp = lane & 3;
  const int win  = (lane >> 2) & 1;
  const int qr2  = lane >> 3;
  const int d0   = dgrp * 8;
  const int mybase = win ? baseB : baseA;
  const unsigned short* vwin = qkvp + 33554432 + mybase;

  half2v o01 = {0,0}, o23 = {0,0}, o45 = {0,0}, o67 = {0,0};
  #pragma unroll
  for (int k = 0; k < 8; ++k) {
    const uint32_t pairw = (uint32_t)__shfl((int)adu, qr2 * 8 + k);
    const half2v ph = bch2(pairw);
    const _Float16 av = win ? ph.y : ph.x;
    const half2v ak2 = {av, av};
    const u32x4 vv = *reinterpret_cast<const u32x4*>(vwin + k * 32 + d0);
    o01 += ak2 * bch2(vv[0]);
    o23 += ak2 * bch2(vv[1]);
    o45 += ak2 * bch2(vv[2]);
    o67 += ak2 * bch2(vv[3]);
  }

  // ---- LePE: depthwise 3x3 on v (zero-pad SAME) at this lane's pixel ----
  const int hq = (half == 0) ? (h0 + qr2) : (h0 + win);
  const int wq = (half == 0) ? (w0 + win) : (w0 + qr2);
  const unsigned short* vplane = qkvp + 33554432;
  const unsigned short* wl = wlep + half * 2304 + n * 32 + d0;
  half2v l01 = {0,0}, l23 = {0,0}, l45 = {0,0}, l67 = {0,0};
  #pragma unroll
  for (int dy = -1; dy <= 1; ++dy) {
    #pragma unroll
    for (int dx = -1; dx <= 1; ++dx) {
      const int hh = hq + dy, ww = wq + dx;
      u32x4 vv = {0u, 0u, 0u, 0u};
      if ((unsigned)hh < 64u && (unsigned)ww < 64u)
        vv = *reinterpret_cast<const u32x4*>(vplane + qkv_idx(half, b, n, hh, ww) + d0);
      const u32x4 wt = *reinterpret_cast<const u32x4*>(wl + ((dy + 1) * 3 + dx + 1) * 256);
      l01 += bch2(wt[0]) * bch2(vv[0]);
      l23 += bch2(wt[1]) * bch2(vv[1]);
      l45 += bch2(wt[2]) * bch2(vv[2]);
      l67 += bch2(wt[3]) * bch2(vv[3]);
    }
  }

  // ---- store token-major for GEMM2 (16B per lane) ----
  const int m = b * 4096 + hq * 64 + wq;
  const int chan0 = half * 256 + n * 32;
  u32x4 r;
  r[0] = __builtin_bit_cast(uint32_t, (half2v)(o01 + l01));
  r[1] = __builtin_bit_cast(uint32_t, (half2v)(o23 + l23));
  r[2] = __builtin_bit_cast(uint32_t, (half2v)(o45 + l45));
  r[3] = __builtin_bit_cast(uint32_t, (half2v)(o67 + l67));
  *reinterpret_cast<u32x4*>(outp + (size_t)m * 512 + chan0 + d0) = r;
}

// ---------- launch ----------
extern "C" void kernel_launch(void* const* d_in, const int* in_sizes, int n_in,
                              void* d_out, int out_size, void* d_ws, size_t ws_size,
                              hipStream_t stream) {
  const float* x      = (const float*)d_in[0];   // (8, 4096, 512)
  const float* w_qkv  = (const float*)d_in[1];   // (1536, 512)
  const float* w_proj = (const float*)d_in[2];   // (512, 512)
  const float* b_proj = (const float*)d_in[3];   // (512,)
  const float* lepe_h = (const float*)d_in[4];   // (3,3,1,256)
  const float* lepe_v = (const float*)d_in[5];   // (3,3,1,256)
  float* out = (float*)d_out;                    // (8, 4096, 512) f32

  char* ws = (char*)d_ws;
  unsigned short* qkv_p   = (unsigned short*)ws;                 // 96MB: q|k|v window-major
  unsigned short* xh      = (unsigned short*)(ws + 100663296);   // 32MB: x f16; reused as attn_out
  unsigned short* wqkv_h  = (unsigned short*)(ws + 134217728);   // 1536*512 f16
  unsigned short* wproj_h = (unsigned short*)(ws + 135790592);   // 512*512 f16
  unsigned short* wlep_h  = (unsigned short*)(ws + 136314880);   // 2*9*256 f16

  // casts
  cvt_f32_f16<<<16384, 256, 0, stream>>>(x, xh, 4194304);
  cvt_f32_f16<<<768,   256, 0, stream>>>(w_qkv, wqkv_h, 196608);
  cvt_f32_f16<<<256,   256, 0, stream>>>(w_proj, wproj_h, 65536);
  cvt_f32_f16<<<3,     256, 0, stream>>>(lepe_h, wlep_h, 576);
  cvt_f32_f16<<<3,     256, 0, stream>>>(lepe_v, wlep_h + 2304, 576);

  // qkv = x @ w_qkv^T -> window-major f16 (8-phase 256^2; grid 128*6=768)
  gemm8<1><<<768, 512, 0, stream>>>(
      xh, wqkv_h, qkv_p, nullptr, nullptr, 32768, 1536);

  // stripe attention + LePE -> attn_out token-major (xh dead -> reuse)
  attn_lepe<<<8192, 256, 0, stream>>>(qkv_p, wlep_h, xh);

  // out = attn_out @ w_proj^T + b_proj -> f32 (grid 128*2=256)
  gemm8<0><<<256, 512, 0, stream>>>(
      xh, wproj_h, nullptr, out, b_proj, 32768, 512);
}